// Round 16
// baseline (142.280 us; speedup 1.0000x reference)
//
#include <hip/hip_runtime.h>

typedef unsigned short u16t;
typedef unsigned int   u32t;
typedef __bf16 bf16x8 __attribute__((ext_vector_type(8)));
typedef float  f32x4  __attribute__((ext_vector_type(4)));

#define NB   64
#define DIN  1024
#define DOUT 256
#define EPS  1e-4f   // LR*LR
#define KP   68      // LDS row stride in u16 (34 dw == 2 mod 32; proven pattern)

#define OUT_STATE (NB*DIN*DOUT)
#define OUT_LL    (OUT_STATE + 1)
#define OUT_RR    (OUT_LL + NB*DIN)

__device__ __forceinline__ u16t f2b(float x) {
    u32t u = __builtin_bit_cast(u32t, x);
    u += 0x7FFFu + ((u >> 16) & 1u);          // RTNE
    return (u16t)(u >> 16);
}
__device__ __forceinline__ float b2f(u16t h) {
    return __builtin_bit_cast(float, ((u32t)h) << 16);
}
__device__ __forceinline__ bf16x8 ld_frag(const u16t* p) {
    uint2 lo = *(const uint2*)(p);
    uint2 hi = *(const uint2*)(p + 4);
    union { uint4 u; bf16x8 v; } x;
    x.u = make_uint4(lo.x, lo.y, hi.x, hi.y);
    return x.v;
}
__device__ __forceinline__ void st8(u16t* p, u32t a, u32t b) {
    *(uint2*)(p) = make_uint2(a, b);
}

// ============================================================
// K1 (k_prep): stats + GH = bf16(a_i*grad) (R8-proven form).
//   row moments -> ll (out), GH write, col partials CP (128 slots/n).
// grid 2048 = (32 chunks x 64 n), block 256 (4 waves x 8 rows).
// ============================================================
__global__ __launch_bounds__(256) void k_prep(
    const float* __restrict__ grad, const float* __restrict__ L0,
    float* __restrict__ out, u16t* __restrict__ GH, float* __restrict__ CP)
{
    const int bid = blockIdx.x;
    const int n = bid & 63;
    const int chunk = bid >> 6;                 // 0..31
    const int wave = threadIdx.x >> 6, lane = threadIdx.x & 63;
    const float* gb = grad + ((size_t)n << 18);
    u16t* GHn = GH + ((size_t)n << 18);

    float4 cacc = {0.f, 0.f, 0.f, 0.f};
    const int i0 = chunk * 32 + wave * 8;
    #pragma unroll
    for (int r = 0; r < 8; ++r) {
        const int i = i0 + r;
        const float4 v = *(const float4*)(gb + (size_t)i * 256 + lane * 4);
        float s = v.x*v.x + v.y*v.y + v.z*v.z + v.w*v.w;
        cacc.x += v.x*v.x; cacc.y += v.y*v.y; cacc.z += v.z*v.z; cacc.w += v.w*v.w;
        #pragma unroll
        for (int off = 32; off; off >>= 1) s += __shfl_xor(s, off);
        const float l0 = L0[n * DIN + i];
        const float ll = fmaxf(l0, 0.5f * l0 + s * (0.5f / DOUT));
        const float a  = rsqrtf(sqrtf(ll));
        ushort4 g4v = { f2b(v.x*a), f2b(v.y*a), f2b(v.z*a), f2b(v.w*a) };
        *(ushort4*)(GHn + (size_t)i * 256 + lane * 4) = g4v;
        if (lane == 0) out[OUT_LL + n * DIN + i] = ll;
    }
    const int slot = chunk * 4 + wave;          // 0..127
    *(float4*)(CP + ((size_t)(n * 128 + slot)) * 256 + lane * 4) = cacc;
}

// ============================================================
// K2: reduce 128 col partials -> rr (out), BS = rr^-1/4 ; copy state
// ============================================================
__global__ __launch_bounds__(256) void k_cols(
    const float* __restrict__ R0, const float* __restrict__ state,
    float* __restrict__ out, float* __restrict__ BS, const float* __restrict__ CP)
{
    const int n = blockIdx.x, o = threadIdx.x;
    const float* cp = CP + (size_t)n * 128 * 256 + o;
    float s = 0.f;
    #pragma unroll 8
    for (int k = 0; k < 128; ++k) s += cp[k * 256];
    const float r0 = R0[n * DOUT + o];
    const float rr = fmaxf(r0, 0.5f * r0 + s * (0.5f / DIN));
    out[OUT_RR + n * DOUT + o] = rr;
    BS[n * DOUT + o] = rsqrtf(sqrtf(rr));
    if (n == 0 && o == 0) out[OUT_STATE] = state[0];
}

// ============================================================
// G1 (k_T): TT[o][p] = b[o] * sum_i GH[i][o] * M[i][p]
// NEW staging: coalesced ROW reads (GH uint2: 2 rows x 256B per
// wave-instr; M float4: 4 rows x 256B), transpose done at the LDS
// write with row-permutation rho(o)=(o&3)*32+(o>>2) [sB:
// rho64(p)=(p&3)*16+(p>>2)] -> scalar u16 writes are 2-way bank
// (free: bank=(2q+il>>1)%32). Fragment reads index rho(row); their
// 4-way conflict is on only 12 b64 reads/chunk (cheap).
// tile 128o x 64p, BK=64 (16 chunks). grid 512 = (8 tiles x 64 n).
// ============================================================
__global__ __launch_bounds__(256, 4) void k_T(
    const u16t* __restrict__ GH, const float* __restrict__ M,
    const float* __restrict__ BS, u16t* __restrict__ TT)
{
    __shared__ u16t sA[128 * KP];   // [rho(o)][i]
    __shared__ u16t sB[64 * KP];    // [rho64(p)][i]
    const int bid = blockIdx.x;
    const int n = bid & 63;
    const int tile = bid >> 6;                  // 0..7: 2 o-tiles x 4 p-tiles
    const int o0 = (tile & 1) * 128, p0 = (tile >> 1) * 64;
    const int t = threadIdx.x, lane = t & 63, w = t >> 6;
    const int wr = w >> 1, wc = w & 1, t16 = lane & 15, g4 = lane >> 4;
    const u16t* GHn = GH + ((size_t)n << 18);
    const float* Mn = M + ((size_t)n << 18);
    f32x4 acc[4][2] = {};

    for (int ch = 0; ch < 16; ++ch) {
        const int ib = ch * 64;
        __syncthreads();
        // GH rows -> sA transposed: 8 x uint2 per thread
        #pragma unroll
        for (int j = 0; j < 8; ++j) {
            const int s = j * 256 + t;
            const int il = s >> 5, q = s & 31;
            const uint2 g = *(const uint2*)(GHn + (size_t)(ib + il) * 256 + o0 + 4 * q);
            sA[((0 << 5) + q) * KP + il] = (u16t)(g.x & 0xffffu);
            sA[((1 << 5) + q) * KP + il] = (u16t)(g.x >> 16);
            sA[((2 << 5) + q) * KP + il] = (u16t)(g.y & 0xffffu);
            sA[((3 << 5) + q) * KP + il] = (u16t)(g.y >> 16);
        }
        // M rows -> sB transposed: 4 x float4 per thread
        #pragma unroll
        for (int j = 0; j < 4; ++j) {
            const int s = j * 256 + t;
            const int il = s >> 4, q = s & 15;
            const float4 m = *(const float4*)(Mn + (size_t)(ib + il) * 256 + p0 + 4 * q);
            sB[((0 << 4) + q) * KP + il] = f2b(m.x);
            sB[((1 << 4) + q) * KP + il] = f2b(m.y);
            sB[((2 << 4) + q) * KP + il] = f2b(m.z);
            sB[((3 << 4) + q) * KP + il] = f2b(m.w);
        }
        __syncthreads();
        #pragma unroll
        for (int kb = 0; kb < 2; ++kb) {
            const int ko = kb * 32 + g4 * 8;
            bf16x8 fa[4], fb[2];
            #pragma unroll
            for (int fm = 0; fm < 4; ++fm) {
                const int oro = wr * 64 + fm * 16 + t16;
                fa[fm] = ld_frag(sA + (((oro & 3) << 5) + (oro >> 2)) * KP + ko);
            }
            #pragma unroll
            for (int fn = 0; fn < 2; ++fn) {
                const int pro = wc * 32 + fn * 16 + t16;
                fb[fn] = ld_frag(sB + (((pro & 3) << 4) + (pro >> 2)) * KP + ko);
            }
            #pragma unroll
            for (int fm = 0; fm < 4; ++fm)
                #pragma unroll
                for (int fn = 0; fn < 2; ++fn)
                    acc[fm][fn] = __builtin_amdgcn_mfma_f32_16x16x32_bf16(fa[fm], fb[fn], acc[fm][fn], 0, 0, 0);
        }
    }
    const float* bs = BS + n * DOUT;
    u16t* TTn = TT + ((size_t)n << 16);
    #pragma unroll
    for (int fm = 0; fm < 4; ++fm)
        #pragma unroll
        for (int fn = 0; fn < 2; ++fn) {
            const int p = p0 + wc*32 + fn*16 + t16;
            #pragma unroll
            for (int r = 0; r < 4; ++r) {
                const int o = o0 + wr*64 + fm*16 + g4*4 + r;
                TTn[o * 256 + p] = f2b(acc[fm][fn][r] * bs[o]);
            }
        }
}

// ============================================================
// G2 (k_fuse): Mnew[i][o] = M[i][o] + EPS*( sum_p M[i][p]*TT[o][p]
//                                           - b_o * b2f(GH[i][o]) )
// (GH = bf16(a_i*grad) -- R8-proven correction path, no fp32 grad read.)
// tile 128i x 128o, K=256 (4 chunks). grid 1024 = (16 tiles x 64 n).
// ============================================================
__global__ __launch_bounds__(256, 3) void k_fuse(
    const float* __restrict__ M, const u16t* __restrict__ GH,
    const float* __restrict__ BS, const u16t* __restrict__ TT,
    float* __restrict__ out)
{
    __shared__ u16t sA[128 * KP];   // [i][p]
    __shared__ u16t sB[128 * KP];   // [o][p]
    const int bid = blockIdx.x;
    const int n = bid & 63;
    const int tile = bid >> 6;                  // 0..15: 8 i-tiles x 2 o-tiles
    const int i0 = (tile & 7) * 128, o0 = (tile >> 3) * 128;
    const int t = threadIdx.x, lane = t & 63, w = t >> 6;
    const int wr = w >> 1, wc = w & 1, t16 = lane & 15, g4 = lane >> 4;
    const float* Mn = M + ((size_t)n << 18);
    const u16t* GHn = GH + ((size_t)n << 18);
    const u16t* TTn = TT + ((size_t)n << 16);
    float4 rMa[8];
    uint4  rTb[4];
    f32x4 acc[4][4] = {};

#define FU_LOAD(ch) { const int pb_ = (ch) * 64; \
    _Pragma("unroll") for (int j = 0; j < 8; ++j) { \
        const int s = j * 256 + t, row = s >> 4, c4 = (s & 15) * 4; \
        rMa[j] = *(const float4*)(Mn + (size_t)(i0 + row) * 256 + pb_ + c4); } \
    _Pragma("unroll") for (int j = 0; j < 4; ++j) { \
        const int s = j * 256 + t, row = s >> 3, c8 = (s & 7) * 8; \
        rTb[j] = *(const uint4*)(TTn + (size_t)(o0 + row) * 256 + pb_ + c8); } }

    FU_LOAD(0);
    for (int ch = 0; ch < 4; ++ch) {
        __syncthreads();
        #pragma unroll
        for (int j = 0; j < 8; ++j) {
            const int s = j * 256 + t, row = s >> 4, c4 = (s & 15) * 4;
            const float4 v = rMa[j];
            ushort4 h = { f2b(v.x), f2b(v.y), f2b(v.z), f2b(v.w) };
            *(ushort4*)(sA + row * KP + c4) = h;
        }
        #pragma unroll
        for (int j = 0; j < 4; ++j) {
            const int s = j * 256 + t, row = s >> 3, c8 = (s & 7) * 8;
            st8(sB + row * KP + c8,     rTb[j].x, rTb[j].y);
            st8(sB + row * KP + c8 + 4, rTb[j].z, rTb[j].w);
        }
        __syncthreads();
        if (ch < 3) FU_LOAD(ch + 1);
        #pragma unroll
        for (int kb = 0; kb < 2; ++kb) {
            const int ko = kb * 32 + g4 * 8;
            bf16x8 fa[4], fb[4];
            #pragma unroll
            for (int fm = 0; fm < 4; ++fm)
                fa[fm] = ld_frag(sA + (wr*64 + fm*16 + t16) * KP + ko);
            #pragma unroll
            for (int fn = 0; fn < 4; ++fn)
                fb[fn] = ld_frag(sB + (wc*64 + fn*16 + t16) * KP + ko);
            #pragma unroll
            for (int fm = 0; fm < 4; ++fm)
                #pragma unroll
                for (int fn = 0; fn < 4; ++fn)
                    acc[fm][fn] = __builtin_amdgcn_mfma_f32_16x16x32_bf16(fa[fm], fb[fn], acc[fm][fn], 0, 0, 0);
        }
    }
    const float* bs = BS + n * DOUT;
    float* outn = out + ((size_t)n << 18);
    #pragma unroll
    for (int fm = 0; fm < 4; ++fm)
        #pragma unroll
        for (int fn = 0; fn < 4; ++fn) {
            const int o = o0 + wc*64 + fn*16 + t16;
            const float bo = bs[o];
            #pragma unroll
            for (int r = 0; r < 4; ++r) {
                const int i = i0 + wr*64 + fm*16 + g4*4 + r;
                const size_t idx = (size_t)i * 256 + o;
                outn[idx] = Mn[idx] + EPS * (acc[fm][fn][r] - bo * b2f(GHn[idx]));
            }
        }
}

extern "C" void kernel_launch(void* const* d_in, const int* in_sizes, int n_in,
                              void* d_out, int out_size, void* d_ws, size_t ws_size,
                              hipStream_t stream) {
    const float* grad  = (const float*)d_in[0];
    const float* M     = (const float*)d_in[1];
    const float* state = (const float*)d_in[2];
    const float* L0    = (const float*)d_in[3];
    const float* R0    = (const float*)d_in[4];
    float* out = (float*)d_out;
    char* wsb = (char*)d_ws;

    // region map (~48.1 MB):
    u16t*  GH = (u16t*)(wsb);                          // [0,32MB)   GH[n][i][o]
    u16t*  TT = (u16t*)(wsb + ((size_t)32 << 20));     // [32,40MB)  TT[n][o][p]
    float* CP = (float*)(wsb + ((size_t)40 << 20));    // [40,48MB)  CP[n][128][256]
    float* BS = (float*)(wsb + ((size_t)48 << 20));    // 64KB

    k_prep <<<2048, 256, 0, stream>>>(grad, L0, out, GH, CP);
    k_cols <<<64,   256, 0, stream>>>(R0, state, out, BS, CP);
    k_T    <<<512,  256, 0, stream>>>(GH, M, BS, TT);
    k_fuse <<<1024, 256, 0, stream>>>(M, GH, BS, TT, out);
}

// Round 17
// 92.238 us; speedup vs baseline: 1.5425x; 1.5425x over previous
//
#include <hip/hip_runtime.h>

typedef unsigned short u16t;
typedef unsigned int   u32t;
typedef __bf16 bf16x8 __attribute__((ext_vector_type(8)));
typedef float  f32x4  __attribute__((ext_vector_type(4)));

#define NB   64
#define DIN  1024
#define DOUT 256
#define EPS  1e-4f   // LR*LR
#define KP   68      // LDS row stride in u16 (k_fuse; proven 0-conflict)
#define SUBP 2064    // k_T subtile stride bytes: 64 rows x 32B + 16B pad (16B-aligned, +4dw skew)

#define OUT_STATE (NB*DIN*DOUT)
#define OUT_LL    (OUT_STATE + 1)
#define OUT_RR    (OUT_LL + NB*DIN)

__device__ __forceinline__ u16t f2b(float x) {
    u32t u = __builtin_bit_cast(u32t, x);
    u += 0x7FFFu + ((u >> 16) & 1u);          // RTNE
    return (u16t)(u >> 16);
}
__device__ __forceinline__ float b2f(u16t h) {
    return __builtin_bit_cast(float, ((u32t)h) << 16);
}
__device__ __forceinline__ bf16x8 ld_frag(const u16t* p) {
    uint2 lo = *(const uint2*)(p);
    uint2 hi = *(const uint2*)(p + 4);
    union { uint4 u; bf16x8 v; } x;
    x.u = make_uint4(lo.x, lo.y, hi.x, hi.y);
    return x.v;
}
__device__ __forceinline__ void st8(u16t* p, u32t a, u32t b) {
    *(uint2*)(p) = make_uint2(a, b);
}

// ============================================================
// K1 (k_prep): stats + GH = bf16(a_i*grad) (R8/R15-proven form).
// grid 2048 = (32 chunks x 64 n), block 256 (4 waves x 8 rows).
// ============================================================
__global__ __launch_bounds__(256) void k_prep(
    const float* __restrict__ grad, const float* __restrict__ L0,
    float* __restrict__ out, u16t* __restrict__ GH, float* __restrict__ CP)
{
    const int bid = blockIdx.x;
    const int n = bid & 63;
    const int chunk = bid >> 6;                 // 0..31
    const int wave = threadIdx.x >> 6, lane = threadIdx.x & 63;
    const float* gb = grad + ((size_t)n << 18);
    u16t* GHn = GH + ((size_t)n << 18);

    float4 cacc = {0.f, 0.f, 0.f, 0.f};
    const int i0 = chunk * 32 + wave * 8;
    #pragma unroll
    for (int r = 0; r < 8; ++r) {
        const int i = i0 + r;
        const float4 v = *(const float4*)(gb + (size_t)i * 256 + lane * 4);
        float s = v.x*v.x + v.y*v.y + v.z*v.z + v.w*v.w;
        cacc.x += v.x*v.x; cacc.y += v.y*v.y; cacc.z += v.z*v.z; cacc.w += v.w*v.w;
        #pragma unroll
        for (int off = 32; off; off >>= 1) s += __shfl_xor(s, off);
        const float l0 = L0[n * DIN + i];
        const float ll = fmaxf(l0, 0.5f * l0 + s * (0.5f / DOUT));
        const float a  = rsqrtf(sqrtf(ll));
        ushort4 g4v = { f2b(v.x*a), f2b(v.y*a), f2b(v.z*a), f2b(v.w*a) };
        *(ushort4*)(GHn + (size_t)i * 256 + lane * 4) = g4v;
        if (lane == 0) out[OUT_LL + n * DIN + i] = ll;
    }
    const int slot = chunk * 4 + wave;          // 0..127
    *(float4*)(CP + ((size_t)(n * 128 + slot)) * 256 + lane * 4) = cacc;
}

// ============================================================
// K2: reduce 128 col partials -> rr (out), BS = rr^-1/4 ; copy state
// ============================================================
__global__ __launch_bounds__(256) void k_cols(
    const float* __restrict__ R0, const float* __restrict__ state,
    float* __restrict__ out, float* __restrict__ BS, const float* __restrict__ CP)
{
    const int n = blockIdx.x, o = threadIdx.x;
    const float* cp = CP + (size_t)n * 128 * 256 + o;
    float s = 0.f;
    #pragma unroll 8
    for (int k = 0; k < 128; ++k) s += cp[k * 256];
    const float r0 = R0[n * DOUT + o];
    const float rr = fmaxf(r0, 0.5f * r0 + s * (0.5f / DIN));
    out[OUT_RR + n * DOUT + o] = rr;
    BS[n * DOUT + o] = rsqrtf(sqrtf(rr));
    if (n == 0 && o == 0) out[OUT_STATE] = state[0];
}

// ============================================================
// G1 (k_T): TT[o][p] = b[o] * sum_i GH[i][o] * M[i][p]
// ZERO-transpose staging: GH rows -> LDS via uint4 (coalesced),
// M rows -> cvt -> ushort4. LDS layout: 16-col subtiles [sub][i][16]
// bf16, i-stride 32B (= tr-read HW stride), sub stride SUBP.
// Fragments via ds_read_b64_tr_b16 (lane l: col l&15, rows +0..3;
// second read offset:128 = rows +4..7). waitcnt+sched_barrier before
// MFMA per rule 18. tile 128o x 64p, BK=64 (16 chunks). grid 512.
// ============================================================
__global__ __launch_bounds__(256, 4) void k_T(
    const u16t* __restrict__ GH, const float* __restrict__ M,
    const float* __restrict__ BS, u16t* __restrict__ TT)
{
    __shared__ __align__(16) char sAraw[8 * SUBP];   // 8 o-subtiles
    __shared__ __align__(16) char sBraw[4 * SUBP];   // 4 p-subtiles
    const int bid = blockIdx.x;
    const int n = bid & 63;
    const int tile = bid >> 6;                  // 0..7: 2 o-tiles x 4 p-tiles
    const int o0 = (tile & 1) * 128, p0 = (tile >> 1) * 64;
    const int t = threadIdx.x, lane = t & 63, w = t >> 6;
    const int wr = w >> 1, wc = w & 1, t16 = lane & 15, g4 = lane >> 4;
    const u16t* GHn = GH + ((size_t)n << 18);
    const float* Mn = M + ((size_t)n << 18);
    const unsigned sA0 = (unsigned)(uintptr_t)sAraw;
    const unsigned sB0 = (unsigned)(uintptr_t)sBraw;
    const unsigned laneoff = (unsigned)(g4 * 256 + t16 * 2);  // g4*8 rows *32B + col*2B
    f32x4 acc[4][2] = {};

    for (int ch = 0; ch < 16; ++ch) {
        const int ib = ch * 64;
        __syncthreads();
        // stage GH tile 64i x 128o bf16: 4 x uint4, coalesced rows
        #pragma unroll
        for (int j = 0; j < 4; ++j) {
            const int s = j * 256 + t;
            const int il = s >> 4, c8 = s & 15;      // 8-col group
            uint4 v = *(const uint4*)(GHn + (size_t)(ib + il) * 256 + o0 + c8 * 8);
            *(uint4*)(sAraw + (c8 >> 1) * SUBP + il * 32 + (c8 & 1) * 16) = v;
        }
        // stage M tile 64i x 64p fp32 -> bf16: 4 x float4, coalesced rows
        #pragma unroll
        for (int j = 0; j < 4; ++j) {
            const int s = j * 256 + t;
            const int il = s >> 4, c4 = s & 15;      // 4-col group
            const float4 m = *(const float4*)(Mn + (size_t)(ib + il) * 256 + p0 + c4 * 4);
            ushort4 h = { f2b(m.x), f2b(m.y), f2b(m.z), f2b(m.w) };
            *(ushort4*)(sBraw + (c4 >> 2) * SUBP + il * 32 + (c4 & 3) * 8) = h;
        }
        __syncthreads();
        #pragma unroll
        for (int kb = 0; kb < 2; ++kb) {
            const unsigned ko = (unsigned)(kb * 1024);   // kb*32 rows * 32B
            bf16x8 fa[4], fb[2];
            #pragma unroll
            for (int fm = 0; fm < 4; ++fm) {
                const unsigned addr = sA0 + (unsigned)((wr * 4 + fm) * SUBP) + ko + laneoff;
                uint2 lo, hi;
                asm volatile("ds_read_b64_tr_b16 %0, %2\n\t"
                             "ds_read_b64_tr_b16 %1, %2 offset:128"
                             : "=&v"(lo), "=&v"(hi) : "v"(addr) : "memory");
                union { uint4 u; bf16x8 v8; } u; u.u = make_uint4(lo.x, lo.y, hi.x, hi.y);
                fa[fm] = u.v8;
            }
            #pragma unroll
            for (int fn = 0; fn < 2; ++fn) {
                const unsigned addr = sB0 + (unsigned)((wc * 2 + fn) * SUBP) + ko + laneoff;
                uint2 lo, hi;
                asm volatile("ds_read_b64_tr_b16 %0, %2\n\t"
                             "ds_read_b64_tr_b16 %1, %2 offset:128"
                             : "=&v"(lo), "=&v"(hi) : "v"(addr) : "memory");
                union { uint4 u; bf16x8 v8; } u; u.u = make_uint4(lo.x, lo.y, hi.x, hi.y);
                fb[fn] = u.v8;
            }
            asm volatile("s_waitcnt lgkmcnt(0)" ::: "memory");
            __builtin_amdgcn_sched_barrier(0);
            #pragma unroll
            for (int fm = 0; fm < 4; ++fm)
                #pragma unroll
                for (int fn = 0; fn < 2; ++fn)
                    acc[fm][fn] = __builtin_amdgcn_mfma_f32_16x16x32_bf16(fa[fm], fb[fn], acc[fm][fn], 0, 0, 0);
        }
    }
    const float* bs = BS + n * DOUT;
    u16t* TTn = TT + ((size_t)n << 16);
    #pragma unroll
    for (int fm = 0; fm < 4; ++fm)
        #pragma unroll
        for (int fn = 0; fn < 2; ++fn) {
            const int p = p0 + wc*32 + fn*16 + t16;
            #pragma unroll
            for (int r = 0; r < 4; ++r) {
                const int o = o0 + wr*64 + fm*16 + g4*4 + r;
                TTn[o * 256 + p] = f2b(acc[fm][fn][r] * bs[o]);
            }
        }
}

// ============================================================
// G2 (k_fuse): Mnew[i][o] = M[i][o] + EPS*( sum_p M[i][p]*TT[o][p]
//                                           - b_o * b2f(GH[i][o]) )
// (R15-proven, ~29us.) tile 128i x 128o, K=256. grid 1024.
// ============================================================
__global__ __launch_bounds__(256, 3) void k_fuse(
    const float* __restrict__ M, const u16t* __restrict__ GH,
    const float* __restrict__ BS, const u16t* __restrict__ TT,
    float* __restrict__ out)
{
    __shared__ u16t sA[128 * KP];   // [i][p]
    __shared__ u16t sB[128 * KP];   // [o][p]
    const int bid = blockIdx.x;
    const int n = bid & 63;
    const int tile = bid >> 6;                  // 0..15: 8 i-tiles x 2 o-tiles
    const int i0 = (tile & 7) * 128, o0 = (tile >> 3) * 128;
    const int t = threadIdx.x, lane = t & 63, w = t >> 6;
    const int wr = w >> 1, wc = w & 1, t16 = lane & 15, g4 = lane >> 4;
    const float* Mn = M + ((size_t)n << 18);
    const u16t* GHn = GH + ((size_t)n << 18);
    const u16t* TTn = TT + ((size_t)n << 16);
    float4 rMa[8];
    uint4  rTb[4];
    f32x4 acc[4][4] = {};

#define FU_LOAD(ch) { const int pb_ = (ch) * 64; \
    _Pragma("unroll") for (int j = 0; j < 8; ++j) { \
        const int s = j * 256 + t, row = s >> 4, c4 = (s & 15) * 4; \
        rMa[j] = *(const float4*)(Mn + (size_t)(i0 + row) * 256 + pb_ + c4); } \
    _Pragma("unroll") for (int j = 0; j < 4; ++j) { \
        const int s = j * 256 + t, row = s >> 3, c8 = (s & 7) * 8; \
        rTb[j] = *(const uint4*)(TTn + (size_t)(o0 + row) * 256 + pb_ + c8); } }

    FU_LOAD(0);
    for (int ch = 0; ch < 4; ++ch) {
        __syncthreads();
        #pragma unroll
        for (int j = 0; j < 8; ++j) {
            const int s = j * 256 + t, row = s >> 4, c4 = (s & 15) * 4;
            const float4 v = rMa[j];
            ushort4 h = { f2b(v.x), f2b(v.y), f2b(v.z), f2b(v.w) };
            *(ushort4*)(sA + row * KP + c4) = h;
        }
        #pragma unroll
        for (int j = 0; j < 4; ++j) {
            const int s = j * 256 + t, row = s >> 3, c8 = (s & 7) * 8;
            st8(sB + row * KP + c8,     rTb[j].x, rTb[j].y);
            st8(sB + row * KP + c8 + 4, rTb[j].z, rTb[j].w);
        }
        __syncthreads();
        if (ch < 3) FU_LOAD(ch + 1);
        #pragma unroll
        for (int kb = 0; kb < 2; ++kb) {
            const int ko = kb * 32 + g4 * 8;
            bf16x8 fa[4], fb[4];
            #pragma unroll
            for (int fm = 0; fm < 4; ++fm)
                fa[fm] = ld_frag(sA + (wr*64 + fm*16 + t16) * KP + ko);
            #pragma unroll
            for (int fn = 0; fn < 4; ++fn)
                fb[fn] = ld_frag(sB + (wc*64 + fn*16 + t16) * KP + ko);
            #pragma unroll
            for (int fm = 0; fm < 4; ++fm)
                #pragma unroll
                for (int fn = 0; fn < 4; ++fn)
                    acc[fm][fn] = __builtin_amdgcn_mfma_f32_16x16x32_bf16(fa[fm], fb[fn], acc[fm][fn], 0, 0, 0);
        }
    }
    const float* bs = BS + n * DOUT;
    float* outn = out + ((size_t)n << 18);
    #pragma unroll
    for (int fm = 0; fm < 4; ++fm)
        #pragma unroll
        for (int fn = 0; fn < 4; ++fn) {
            const int o = o0 + wc*64 + fn*16 + t16;
            const float bo = bs[o];
            #pragma unroll
            for (int r = 0; r < 4; ++r) {
                const int i = i0 + wr*64 + fm*16 + g4*4 + r;
                const size_t idx = (size_t)i * 256 + o;
                outn[idx] = Mn[idx] + EPS * (acc[fm][fn][r] - bo * b2f(GHn[idx]));
            }
        }
}

extern "C" void kernel_launch(void* const* d_in, const int* in_sizes, int n_in,
                              void* d_out, int out_size, void* d_ws, size_t ws_size,
                              hipStream_t stream) {
    const float* grad  = (const float*)d_in[0];
    const float* M     = (const float*)d_in[1];
    const float* state = (const float*)d_in[2];
    const float* L0    = (const float*)d_in[3];
    const float* R0    = (const float*)d_in[4];
    float* out = (float*)d_out;
    char* wsb = (char*)d_ws;

    // region map (~48.1 MB):
    u16t*  GH = (u16t*)(wsb);                          // [0,32MB)   GH[n][i][o]
    u16t*  TT = (u16t*)(wsb + ((size_t)32 << 20));     // [32,40MB)  TT[n][o][p]
    float* CP = (float*)(wsb + ((size_t)40 << 20));    // [40,48MB)  CP[n][128][256]
    float* BS = (float*)(wsb + ((size_t)48 << 20));    // 64KB

    k_prep <<<2048, 256, 0, stream>>>(grad, L0, out, GH, CP);
    k_cols <<<64,   256, 0, stream>>>(R0, state, out, BS, CP);
    k_T    <<<512,  256, 0, stream>>>(GH, M, BS, TT);
    k_fuse <<<1024, 256, 0, stream>>>(M, GH, BS, TT, out);
}